// Round 11
// baseline (613.054 us; speedup 1.0000x reference)
//
#include <hip/hip_runtime.h>
#include <hip/hip_bf16.h>
#include <cmath>

#define U16 unsigned short

typedef __bf16 bf16x8_t __attribute__((ext_vector_type(8)));
typedef float f32x4_t __attribute__((ext_vector_type(4)));

union Frag { uint4 u4; unsigned u[4]; bf16x8_t b8; U16 s[8]; };

__device__ __forceinline__ float b2f(U16 u) {
  union { unsigned int i; float f; } x; x.i = ((unsigned int)u) << 16; return x.f;
}
__device__ __forceinline__ U16 f2b(float f) {
  union { float f; unsigned int i; } x; x.f = f;
  unsigned int r = x.i + 0x7FFFu + ((x.i >> 16) & 1u);
  return (U16)(r >> 16);
}
__device__ __forceinline__ unsigned cvt_pk_bf16(float a, float b) {
  union { __hip_bfloat162 h2; unsigned u; } x;
  x.h2 = __float22bfloat162_rn(make_float2(a, b));
  return x.u;
}
__device__ __forceinline__ float fast_silu(float z) {
  return z * __builtin_amdgcn_rcpf(1.f + __expf(-z));
}
__device__ __forceinline__ void load_lds16(const U16* g, U16* l) {
  __builtin_amdgcn_global_load_lds((const __attribute__((address_space(1))) void*)g,
                                   (__attribute__((address_space(3))) void*)l, 16, 0, 0);
}

// ---------------- device-scope grid barrier (co-resident grid; m20 atomics) ----------------
__device__ __forceinline__ void gbar(unsigned* cnt, int idx, unsigned nb) {
  __syncthreads();
  if (threadIdx.x == 0) {
    __threadfence();  // agent release: L2 writeback -> writes visible device-wide
    atomicAdd(&cnt[idx * 16], 1u);
    while (__hip_atomic_load(&cnt[idx * 16], __ATOMIC_RELAXED,
                             __HIP_MEMORY_SCOPE_AGENT) < nb)
      __builtin_amdgcn_s_sleep(2);
    __threadfence();  // agent acquire: invalidate stale caches
  }
  __syncthreads();
}

// ---------------- layernorm row (shfl reduce) ----------------
__device__ __forceinline__ void ln_row(int row, const float* X, const float* gam,
                                       const float* bet, U16* Y) {
  int tid = threadIdx.x, lane = tid & 63, wave = tid >> 6;
  __shared__ float p1[4], p2[4];
  __syncthreads();  // protect p1/p2 across loop iterations
  float v[3];
#pragma unroll
  for (int j = 0; j < 3; ++j) v[j] = X[(size_t)row * 768 + tid + j * 256];
  float s1 = v[0] + v[1] + v[2];
  float s2 = v[0] * v[0] + v[1] * v[1] + v[2] * v[2];
#pragma unroll
  for (int m = 32; m > 0; m >>= 1) {
    s1 += __shfl_xor(s1, m);
    s2 += __shfl_xor(s2, m);
  }
  if (lane == 0) { p1[wave] = s1; p2[wave] = s2; }
  __syncthreads();
  float t1 = p1[0] + p1[1] + p1[2] + p1[3];
  float t2 = p2[0] + p2[1] + p2[2] + p2[3];
  float mean = t1 * (1.f / 768.f);
  float var = t2 * (1.f / 768.f) - mean * mean;
  float rstd = rsqrtf(var + 1e-5f);
#pragma unroll
  for (int j = 0; j < 3; ++j) {
    int c = tid + j * 256;
    Y[(size_t)row * 768 + c] = f2b((v[j] - mean) * rstd * gam[c] + bet[c]);
  }
}

// ---------------- weight-prep item ----------------
__device__ void prep_item(int bid, float* tile,  // tile: 32*33 floats in smem
                          const float* qkv_w, const float* out_w, const float* g1w,
                          const float* g2w, const float* ff1w, const float* ff2w,
                          const float* rb1w, const float* rb2w, const float* qkv_b,
                          const float* gate_b1, U16* qkv_wT, U16* out_wT, U16* g1wT,
                          U16* g2wT, U16* ff1wT, U16* ff2wT, U16* rb1wT, U16* rb2wL,
                          float* qg_bias, const float* x, const float* ln1_g,
                          const float* ln1_b, U16* xn) {
  if (bid >= 5868) { ln_row(bid - 5868, x, ln1_g, ln1_b, xn); return; }
  if (bid >= 5856) {
    int idx = (bid - 5856) * 256 + threadIdx.x;
    qg_bias[idx] = (idx < 2304) ? qkv_b[idx] : gate_b1[idx - 2304];
    return;
  }
  if (bid >= 5808) {
    int idx = (bid - 5808) * 256 + threadIdx.x;
    int j = idx & 7, lane = (idx >> 3) & 63, pp = idx >> 9;
    int row = lane & 15, col = pp * 32 + ((lane >> 4) << 3) + j;
    rb2wL[idx] = (row < 12) ? f2b(rb2w[col * 12 + row]) : (U16)0;
    return;
  }
  const float* in; U16* out; int R, C, base;
  if (bid < 1728)      { in = qkv_w; out = qkv_wT; R = 768;  C = 2304; base = 0; }
  else if (bid < 2304) { in = out_w; out = out_wT; R = 768;  C = 768;  base = 1728; }
  else if (bid < 2880) { in = g1w;   out = g1wT;   R = 768;  C = 768;  base = 2304; }
  else if (bid < 3456) { in = g2w;   out = g2wT;   R = 768;  C = 768;  base = 2880; }
  else if (bid < 4608) { in = ff1w;  out = ff1wT;  R = 768;  C = 1536; base = 3456; }
  else if (bid < 5760) { in = ff2w;  out = ff2wT;  R = 1536; C = 768;  base = 4608; }
  else                 { in = rb1w;  out = rb1wT;  R = 64;   C = 768;  base = 5760; }
  int bx = bid - base, tilesx = C / 32;
  int c0 = (bx % tilesx) * 32, r0 = (bx / tilesx) * 32;
  int tx = threadIdx.x & 31, ty = threadIdx.x >> 5;
  __syncthreads();  // protect tile across loop iterations
#pragma unroll
  for (int yy = 0; yy < 4; ++yy)
    tile[(ty + yy * 8) * 33 + tx] = in[(size_t)(r0 + ty + yy * 8) * C + c0 + tx];
  __syncthreads();
#pragma unroll
  for (int yy = 0; yy < 4; ++yy)
    out[(size_t)(c0 + ty + yy * 8) * R + r0 + tx] = f2b(tile[tx * 33 + ty + yy * 8]);
}

// ---------------- double-buffered bf16-MFMA GEMM core ----------------
// EPI: 0=none 2=gelu 4=z+other(fp32 out) 5=fused qkv/gate1 6=sigmoid->bf16
template <int EPI, bool OUTF32>
__device__ void gemm_core(U16* sA, U16* sB,  // each [2*2048]
                          const U16* A, const U16* BT, const float* bias,
                          const float* other, void* Cout, float* Cout2,
                          int N, int K, int bx, int by) {
  int tid = threadIdx.x;
  int lane = tid & 63, wave = tid >> 6;
  int m0 = by * 64, n0 = bx * 64;
  int wm = (wave >> 1) * 32, wn = (wave & 1) * 32;
  int lm = lane & 15, lq = lane >> 4;
  int srow = tid >> 2, scol = (tid & 3) * 8;
  const U16* ag = A + (size_t)(m0 + srow) * K + scol;
  const U16* bg = BT + (size_t)(n0 + srow) * K + scol;
  int nit = K >> 5;
  __syncthreads();  // LDS reuse across sequential calls within a block
  load_lds16(ag, sA + tid * 8);
  load_lds16(bg, sB + tid * 8);
  f32x4_t acc[2][2] = {};
  for (int i = 0; i < nit; ++i) {
    __syncthreads();
    int cb = (i & 1) * 2048, nb = ((i + 1) & 1) * 2048;
    if (i + 1 < nit) {
      load_lds16(ag + (i + 1) * 32, sA + nb + tid * 8);
      load_lds16(bg + (i + 1) * 32, sB + nb + tid * 8);
    }
    Frag af[2], bf[2];
#pragma unroll
    for (int mt = 0; mt < 2; ++mt)
      af[mt].u4 = *(const uint4*)&sA[cb + (wm + mt * 16 + lm) * 32 + lq * 8];
#pragma unroll
    for (int nt = 0; nt < 2; ++nt)
      bf[nt].u4 = *(const uint4*)&sB[cb + (wn + nt * 16 + lm) * 32 + lq * 8];
#pragma unroll
    for (int mt = 0; mt < 2; ++mt)
#pragma unroll
      for (int nt = 0; nt < 2; ++nt)
        acc[mt][nt] = __builtin_amdgcn_mfma_f32_16x16x32_bf16(af[mt].b8, bf[nt].b8,
                                                              acc[mt][nt], 0, 0, 0);
  }
#pragma unroll
  for (int nt = 0; nt < 2; ++nt) {
    int gc = n0 + wn + nt * 16 + lm;
    float bz = bias[gc];
#pragma unroll
    for (int mt = 0; mt < 2; ++mt) {
#pragma unroll
      for (int r = 0; r < 4; ++r) {
        int gr = m0 + wm + mt * 16 + lq * 4 + r;
        float z = acc[mt][nt][r] + bz;
        if (EPI == 5) {
          if (gc < 2304) Cout2[(size_t)gr * 2304 + gc] = z;
          else ((U16*)Cout)[(size_t)gr * 768 + gc - 2304] = f2b(fast_silu(z));
          continue;
        }
        size_t idx = (size_t)gr * N + gc;
        float o;
        if (EPI == 0) o = z;
        else if (EPI == 2) o = 0.5f * z * (1.f + erff(z * 0.70710678118f));
        else if (EPI == 6) o = __builtin_amdgcn_rcpf(1.f + __expf(-z));
        else o = z + other[idx];
        if (OUTF32) ((float*)Cout)[idx] = o;
        else ((U16*)Cout)[idx] = f2b(o);
      }
    }
  }
}

// ---------------- relative-bias MLP body (512 rows; verified R3-R10) ----------------
__device__ void rb_body(int bid, const float* dist, const U16* w1T, const float* b1,
                        const U16* w2L, const float* b2, float* biasOut) {
  int tid = threadIdx.x;
  int lane = tid & 63, wave = tid >> 6;
  int lm = lane & 15, lq = lane >> 4;
  int r0 = bid * 512;
  float hb = (lm < 12) ? b2[lm] : 0.f;
  Frag bd[8][2];
#pragma unroll
  for (int g = 0; g < 8; ++g) {
    const float* ap = dist + (size_t)(r0 + (wave * 8 + g) * 16 + lm) * 64 + lq * 8;
    float4 v0 = ((const float4*)ap)[0];
    float4 v1 = ((const float4*)ap)[1];
    float4 v2 = ((const float4*)(ap + 32))[0];
    float4 v3 = ((const float4*)(ap + 32))[1];
    bd[g][0].u[0] = cvt_pk_bf16(v0.x, v0.y); bd[g][0].u[1] = cvt_pk_bf16(v0.z, v0.w);
    bd[g][0].u[2] = cvt_pk_bf16(v1.x, v1.y); bd[g][0].u[3] = cvt_pk_bf16(v1.z, v1.w);
    bd[g][1].u[0] = cvt_pk_bf16(v2.x, v2.y); bd[g][1].u[1] = cvt_pk_bf16(v2.z, v2.w);
    bd[g][1].u[2] = cvt_pk_bf16(v3.x, v3.y); bd[g][1].u[3] = cvt_pk_bf16(v3.z, v3.w);
  }
  const U16* w1p0 = w1T + (size_t)(((lm >> 2) << 3) + (lm & 3)) * 64 + lq * 8;
  const U16* w1p1 = w1p0 + 256;
  const U16* w2p = w2L + lane * 8;
  const float* b1p = b1 + lq * 8;
  f32x4_t bacc[8];
#pragma unroll
  for (int g = 0; g < 8; ++g) bacc[g] = {hb, hb, hb, hb};

  auto loadw = [&](int j, Frag& f00, Frag& f01, Frag& f10, Frag& f11, Frag& fwb,
                   float4& fb0, float4& fb1) {
    const U16* p0 = w1p0 + (size_t)j * 2048;
    const U16* p1 = w1p1 + (size_t)j * 2048;
    f00.u4 = *(const uint4*)p0;
    f01.u4 = *(const uint4*)(p0 + 32);
    f10.u4 = *(const uint4*)p1;
    f11.u4 = *(const uint4*)(p1 + 32);
    fwb.u4 = *(const uint4*)(w2p + (size_t)j * 512);
    fb0 = *(const float4*)(b1p + j * 32);
    fb1 = *(const float4*)(b1p + j * 32 + 4);
  };
  auto comp = [&](Frag& f00, Frag& f01, Frag& f10, Frag& f11, Frag& fwb,
                  float4 fb0, float4 fb1) {
    f32x4_t cz0 = {fb0.x, fb0.y, fb0.z, fb0.w};
    f32x4_t cz1 = {fb1.x, fb1.y, fb1.z, fb1.w};
#pragma unroll
    for (int g = 0; g < 8; ++g) {
      f32x4_t z0 = cz0, z1 = cz1;
      z0 = __builtin_amdgcn_mfma_f32_16x16x32_bf16(f00.b8, bd[g][0].b8, z0, 0, 0, 0);
      z0 = __builtin_amdgcn_mfma_f32_16x16x32_bf16(f01.b8, bd[g][1].b8, z0, 0, 0, 0);
      z1 = __builtin_amdgcn_mfma_f32_16x16x32_bf16(f10.b8, bd[g][0].b8, z1, 0, 0, 0);
      z1 = __builtin_amdgcn_mfma_f32_16x16x32_bf16(f11.b8, bd[g][1].b8, z1, 0, 0, 0);
      float s0 = fast_silu(z0[0]), s1 = fast_silu(z0[1]);
      float s2 = fast_silu(z0[2]), s3 = fast_silu(z0[3]);
      float t0 = fast_silu(z1[0]), t1 = fast_silu(z1[1]);
      float t2 = fast_silu(z1[2]), t3 = fast_silu(z1[3]);
      Frag af2;
      af2.u[0] = cvt_pk_bf16(s0, s1); af2.u[1] = cvt_pk_bf16(s2, s3);
      af2.u[2] = cvt_pk_bf16(t0, t1); af2.u[3] = cvt_pk_bf16(t2, t3);
      bacc[g] = __builtin_amdgcn_mfma_f32_16x16x32_bf16(af2.b8, fwb.b8, bacc[g], 0, 0, 0);
    }
  };

  Frag e00, e01, e10, e11, ewb, o00, o01, o10, o11, owb;
  float4 eb0, eb1, ob0, ob1;
  loadw(0, e00, e01, e10, e11, ewb, eb0, eb1);
  for (int pp = 0; pp < 24; pp += 2) {
    loadw(pp + 1, o00, o01, o10, o11, owb, ob0, ob1);
    comp(e00, e01, e10, e11, ewb, eb0, eb1);
    if (pp + 2 < 24) loadw(pp + 2, e00, e01, e10, e11, ewb, eb0, eb1);
    comp(o00, o01, o10, o11, owb, ob0, ob1);
  }
  if (lm < 12) {
#pragma unroll
    for (int g = 0; g < 8; ++g) {
#pragma unroll
      for (int r = 0; r < 4; ++r) {
        int gr = r0 + (wave * 8 + g) * 16 + lq * 4 + r;
        int b = gr >> 16, rem = gr & 65535, i = rem >> 8, j = rem & 255;
        biasOut[(((size_t)b * 12 + lm) * 256 + i) * 256 + j] = bacc[g][r];
      }
    }
  }
}

// ---------------- attention body (in-LDS K transpose; verified R8-R10) ----------------
__device__ void attn_body(unsigned char* smem, int bid, const float* qkv,
                          const float* biasB, const int* mask, float* ctx) {
  U16* sK = (U16*)smem;                          // 64*258*2 = 33024 B
  float(*sQ)[66] = (float(*)[66])(smem + 33024); // 16*66*4 = 4224 B
  float* sP = (float*)(smem + 33024 + 4224);     // 16*256*4 = 16384 B
  int tid = threadIdx.x, lane = tid & 63, w = tid >> 6;
  int bh = bid >> 4, b = bh / 12, h = bh % 12;
  int i0 = (bid & 15) * 16;
  __syncthreads();  // LDS reuse across loop iterations
  {
    int r = tid >> 4, c = (tid & 15) * 4;
    *(float4*)&sQ[r][c] =
        *(const float4*)&qkv[((size_t)(b * 256 + i0 + r)) * 2304 + h * 64 + c];
  }
  {
    const float* kr = qkv + ((size_t)(b * 256 + w * 64)) * 2304 + 768 + h * 64 + lane;
#pragma unroll 8
    for (int rr = 0; rr < 64; ++rr) {
      float kv = kr[(size_t)rr * 2304];
      sK[lane * 258 + w * 64 + rr] = (U16)cvt_pk_bf16(kv, kv);
    }
  }
  __syncthreads();
  int iw = i0 + w * 4;
  float lacc[4][4] = {};
#pragma unroll 4
  for (int d = 0; d < 64; ++d) {
    float k0 = b2f(sK[d * 258 + lane]);
    float k1 = b2f(sK[d * 258 + 64 + lane]);
    float k2 = b2f(sK[d * 258 + 128 + lane]);
    float k3 = b2f(sK[d * 258 + 192 + lane]);
#pragma unroll
    for (int qi = 0; qi < 4; ++qi) {
      float qv = sQ[w * 4 + qi][d];
      lacc[qi][0] += qv * k0;
      lacc[qi][1] += qv * k1;
      lacc[qi][2] += qv * k2;
      lacc[qi][3] += qv * k3;
    }
  }
#pragma unroll
  for (int qi = 0; qi < 4; ++qi) {
    int gi = iw + qi;
    const float* brow = biasB + (((size_t)b * 12 + h) * 256 + gi) * 256;
    const int* mrow = mask + ((size_t)b * 256 + gi) * 256;
    float lg[4];
#pragma unroll
    for (int jc = 0; jc < 4; ++jc) {
      float lv = lacc[qi][jc] * 0.125f + brow[jc * 64 + lane];
      lg[jc] = mrow[jc * 64 + lane] ? lv : -1e30f;
    }
    float mx = fmaxf(fmaxf(lg[0], lg[1]), fmaxf(lg[2], lg[3]));
#pragma unroll
    for (int m = 32; m > 0; m >>= 1) mx = fmaxf(mx, __shfl_xor(mx, m));
    float e[4], sum = 0.f;
#pragma unroll
    for (int jc = 0; jc < 4; ++jc) { e[jc] = __expf(lg[jc] - mx); sum += e[jc]; }
#pragma unroll
    for (int m = 32; m > 0; m >>= 1) sum += __shfl_xor(sum, m);
    float inv = __builtin_amdgcn_rcpf(sum);
#pragma unroll
    for (int jc = 0; jc < 4; ++jc) sP[(w * 4 + qi) * 256 + jc * 64 + lane] = e[jc] * inv;
  }
  float ca[4] = {0.f, 0.f, 0.f, 0.f};
  const float* vcol = qkv + (size_t)b * 256 * 2304 + 1536 + h * 64 + lane;
#pragma unroll 2
  for (int j4 = 0; j4 < 256; j4 += 4) {
    float4 p0 = *(const float4*)&sP[(w * 4 + 0) * 256 + j4];
    float4 p1 = *(const float4*)&sP[(w * 4 + 1) * 256 + j4];
    float4 p2 = *(const float4*)&sP[(w * 4 + 2) * 256 + j4];
    float4 p3 = *(const float4*)&sP[(w * 4 + 3) * 256 + j4];
    const float* pp0 = (const float*)&p0;
    const float* pp1 = (const float*)&p1;
    const float* pp2 = (const float*)&p2;
    const float* pp3 = (const float*)&p3;
#pragma unroll
    for (int jj = 0; jj < 4; ++jj) {
      float v = vcol[(size_t)(j4 + jj) * 2304];
      ca[0] += pp0[jj] * v;
      ca[1] += pp1[jj] * v;
      ca[2] += pp2[jj] * v;
      ca[3] += pp3[jj] * v;
    }
  }
#pragma unroll
  for (int qi = 0; qi < 4; ++qi)
    ctx[((size_t)(b * 256 + iw + qi)) * 768 + h * 64 + lane] = ca[qi];
}

// ---------------- out-projection body: x2 = (ctx .* sg) @ out_w + out_b + x ----------------
__device__ void outp_body(unsigned char* smem, int bx, int by, const float* ctx,
                          const U16* sg, const U16* out_wT, const float* out_b,
                          const float* x, float* x2) {
  U16* sA = (U16*)smem;            // 64*32 = 4096 B
  U16* sB = (U16*)(smem + 4096);   // 2*2048*2 = 8192 B
  int tid = threadIdx.x;
  int lane = tid & 63, wave = tid >> 6;
  int m0 = by * 64, n0 = bx * 64;
  int wm = (wave >> 1) * 32, wn = (wave & 1) * 32;
  int lm = lane & 15, lq = lane >> 4;
  int srow = tid >> 2, scol = (tid & 3) * 8;
  const float* cg0 = ctx + (size_t)(m0 + srow) * 768 + scol;
  const U16* sg0 = sg + (size_t)(m0 + srow) * 768 + scol;
  const U16* bg = out_wT + (size_t)(n0 + srow) * 768 + scol;
  __syncthreads();
  load_lds16(bg, sB + tid * 8);
  float4 ca0 = *(const float4*)cg0;
  float4 ca1 = *(const float4*)(cg0 + 4);
  Frag sa; sa.u4 = *(const uint4*)sg0;
  f32x4_t acc[2][2] = {};
  for (int i = 0; i < 24; ++i) {
    __syncthreads();
    int cb = (i & 1) * 2048, nb = ((i + 1) & 1) * 2048;
    if (i + 1 < 24) load_lds16(bg + (i + 1) * 32, sB + nb + tid * 8);
    Frag av;
    av.u[0] = cvt_pk_bf16(ca0.x * b2f(sa.s[0]), ca0.y * b2f(sa.s[1]));
    av.u[1] = cvt_pk_bf16(ca0.z * b2f(sa.s[2]), ca0.w * b2f(sa.s[3]));
    av.u[2] = cvt_pk_bf16(ca1.x * b2f(sa.s[4]), ca1.y * b2f(sa.s[5]));
    av.u[3] = cvt_pk_bf16(ca1.z * b2f(sa.s[6]), ca1.w * b2f(sa.s[7]));
    *(uint4*)&sA[tid * 8] = av.u4;
    if (i + 1 < 24) {
      ca0 = *(const float4*)(cg0 + (i + 1) * 32);
      ca1 = *(const float4*)(cg0 + (i + 1) * 32 + 4);
      sa.u4 = *(const uint4*)(sg0 + (i + 1) * 32);
    }
    __syncthreads();
    Frag af[2], bf[2];
#pragma unroll
    for (int mt = 0; mt < 2; ++mt)
      af[mt].u4 = *(const uint4*)&sA[(wm + mt * 16 + lm) * 32 + lq * 8];
#pragma unroll
    for (int nt = 0; nt < 2; ++nt)
      bf[nt].u4 = *(const uint4*)&sB[cb + (wn + nt * 16 + lm) * 32 + lq * 8];
#pragma unroll
    for (int mt = 0; mt < 2; ++mt)
#pragma unroll
      for (int nt = 0; nt < 2; ++nt)
        acc[mt][nt] = __builtin_amdgcn_mfma_f32_16x16x32_bf16(af[mt].b8, bf[nt].b8,
                                                              acc[mt][nt], 0, 0, 0);
  }
#pragma unroll
  for (int nt = 0; nt < 2; ++nt) {
    int gc = n0 + wn + nt * 16 + lm;
    float bz = out_b[gc];
#pragma unroll
    for (int mt = 0; mt < 2; ++mt) {
#pragma unroll
      for (int r = 0; r < 4; ++r) {
        int gr = m0 + wm + mt * 16 + lq * 4 + r;
        size_t idx = (size_t)gr * 768 + gc;
        x2[idx] = acc[mt][nt][r] + bz + x[idx];
      }
    }
  }
}

// ---------------- the megakernel: 7 phases, 6 global barriers, one launch ----------------
__global__ __launch_bounds__(256, 2) void mega_kernel(
    const float* x, const float* dist, const int* mask,
    const float* qkv_w, const float* qkv_b, const float* out_w, const float* out_b,
    const float* rb_w1, const float* rb_b1, const float* rb_w2, const float* rb_b2,
    const float* gate_w1, const float* gate_b1, const float* gate_w2,
    const float* gate_b2, const float* ff_w1, const float* ff_b1, const float* ff_w2,
    const float* ff_b2, const float* ln1_g, const float* ln1_b, const float* ln2_g,
    const float* ln2_b,
    U16* xn, float* qkvb, U16* qg_wT, float* qg_b, U16* out_wT, U16* g2wT,
    U16* ff1wT, U16* ff2wT, U16* rb1wT, U16* rb2wL, float* biasB, float* ctx,
    U16* g1, U16* sg, float* x2, U16* y, U16* f1, unsigned* counters, float* dout) {
  __shared__ __align__(16) unsigned char smem[53632];
  const unsigned NB = 512;
  U16* g1wT = qg_wT + (size_t)2304 * 768;

  // P0: weight prep + LN1
  for (int it = blockIdx.x; it < 6892; it += NB)
    prep_item(it, (float*)smem, qkv_w, out_w, gate_w1, gate_w2, ff_w1, ff_w2, rb_w1,
              rb_w2, qkv_b, gate_b1, qg_wT, out_wT, g1wT, g2wT, ff1wT, ff2wT, rb1wT,
              rb2wL, qg_b, x, ln1_g, ln1_b, xn);
  gbar(counters, 0, NB);
  // P1: rb bias MLP (512) + fused qkv/gate1 GEMM (768)
  for (int it = blockIdx.x; it < 1280; it += NB) {
    if (it < 512) {
      rb_body(it, dist, rb1wT, rb_b1, rb2wL, rb_b2, biasB);
    } else {
      int g = it - 512;
      gemm_core<5, false>((U16*)smem, (U16*)(smem + 8192), xn, qg_wT, qg_b, nullptr,
                          g1, qkvb, 3072, 768, g % 48, g / 48);
    }
  }
  gbar(counters, 1, NB);
  // P2: attention (768) + gate2' sigmoid GEMM (192)
  for (int it = blockIdx.x; it < 960; it += NB) {
    if (it < 768) {
      attn_body(smem, it, qkvb, biasB, mask, ctx);
    } else {
      int g = it - 768;
      gemm_core<6, false>((U16*)smem, (U16*)(smem + 8192), g1, g2wT, gate_b2, nullptr,
                          sg, nullptr, 768, 768, g % 12, g / 12);
    }
  }
  gbar(counters, 2, NB);
  // P3: out projection with on-the-fly gating + residual
  for (int it = blockIdx.x; it < 192; it += NB)
    outp_body(smem, it % 12, it / 12, ctx, sg, out_wT, out_b, x, x2);
  gbar(counters, 3, NB);
  // P4: LN2
  for (int it = blockIdx.x; it < 1024; it += NB)
    ln_row(it, x2, ln2_g, ln2_b, y);
  gbar(counters, 4, NB);
  // P5: FF1 (gelu)
  for (int it = blockIdx.x; it < 384; it += NB)
    gemm_core<2, false>((U16*)smem, (U16*)(smem + 8192), y, ff1wT, ff_b1, nullptr,
                        f1, nullptr, 1536, 768, it % 24, it / 24);
  gbar(counters, 5, NB);
  // P6: FF2 + residual -> out
  for (int it = blockIdx.x; it < 192; it += NB)
    gemm_core<4, true>((U16*)smem, (U16*)(smem + 8192), f1, ff2wT, ff_b2, x2, dout,
                       nullptr, 768, 1536, it % 12, it / 12);
}

// ---------------- launcher ----------------
extern "C" void kernel_launch(void* const* d_in, const int* in_sizes, int n_in,
                              void* d_out, int out_size, void* d_ws, size_t ws_size,
                              hipStream_t stream) {
  const float* x       = (const float*)d_in[0];
  const float* dist    = (const float*)d_in[1];
  const int* mask      = (const int*)d_in[2];
  const float* qkv_w   = (const float*)d_in[3];
  const float* qkv_b   = (const float*)d_in[4];
  const float* out_w   = (const float*)d_in[5];
  const float* out_b   = (const float*)d_in[6];
  const float* rb_w1   = (const float*)d_in[7];
  const float* rb_b1   = (const float*)d_in[8];
  const float* rb_w2   = (const float*)d_in[9];
  const float* rb_b2   = (const float*)d_in[10];
  const float* gate_w1 = (const float*)d_in[11];
  const float* gate_b1 = (const float*)d_in[12];
  const float* gate_w2 = (const float*)d_in[13];
  const float* gate_b2 = (const float*)d_in[14];
  const float* ff_w1   = (const float*)d_in[15];
  const float* ff_b1   = (const float*)d_in[16];
  const float* ff_w2   = (const float*)d_in[17];
  const float* ff_b2   = (const float*)d_in[18];
  const float* ln1_g   = (const float*)d_in[19];
  const float* ln1_b   = (const float*)d_in[20];
  const float* ln2_g   = (const float*)d_in[21];
  const float* ln2_b   = (const float*)d_in[22];

  char* w = (char*)d_ws;
  auto alloc = [&](size_t bytes) {
    char* p = w;
    w += (bytes + 255) & ~(size_t)255;
    return p;
  };
  unsigned* counters = (unsigned*)alloc(512);  // 6 barriers x 16-word spacing
  U16* xn      = (U16*)alloc(1024 * 768 * 2);
  float* qkvb  = (float*)alloc((size_t)1024 * 2304 * 4);
  U16* qg_wT   = (U16*)alloc((size_t)3072 * 768 * 2);
  float* qg_b  = (float*)alloc(3072 * 4);
  U16* out_wT  = (U16*)alloc(768 * 768 * 2);
  U16* g2wT    = (U16*)alloc(768 * 768 * 2);
  U16* ff1wT   = (U16*)alloc(1536 * 768 * 2);
  U16* ff2wT   = (U16*)alloc(768 * 1536 * 2);
  U16* rb1wT   = (U16*)alloc(768 * 64 * 2);
  U16* rb2wL   = (U16*)alloc(24 * 64 * 8 * 2);
  float* biasB = (float*)alloc((size_t)4 * 12 * 256 * 256 * 4);
  float* ctx   = (float*)alloc(1024 * 768 * 4);
  U16* g1      = (U16*)alloc(1024 * 768 * 2);
  U16* sg      = (U16*)alloc(1024 * 768 * 2);
  float* x2    = (float*)alloc(1024 * 768 * 4);
  U16* y       = (U16*)alloc(1024 * 768 * 2);
  U16* f1      = (U16*)alloc(1024 * 1536 * 2);
  (void)ws_size; (void)in_sizes; (void)n_in; (void)out_size;

  hipMemsetAsync(counters, 0, 512, stream);
  mega_kernel<<<512, 256, 0, stream>>>(
      x, dist, mask, qkv_w, qkv_b, out_w, out_b, rb_w1, rb_b1, rb_w2, rb_b2,
      gate_w1, gate_b1, gate_w2, gate_b2, ff_w1, ff_b1, ff_w2, ff_b2,
      ln1_g, ln1_b, ln2_g, ln2_b,
      xn, qkvb, qg_wT, qg_b, out_wT, g2wT, ff1wT, ff2wT, rb1wT, rb2wL,
      biasB, ctx, g1, sg, x2, y, f1, counters, (float*)d_out);
}

// Round 12
// 425.868 us; speedup vs baseline: 1.4395x; 1.4395x over previous
//
#include <hip/hip_runtime.h>
#include <hip/hip_bf16.h>
#include <cmath>

#define U16 unsigned short

typedef __bf16 bf16x8_t __attribute__((ext_vector_type(8)));
typedef float f32x4_t __attribute__((ext_vector_type(4)));

union Frag { uint4 u4; unsigned u[4]; bf16x8_t b8; U16 s[8]; };

__device__ __forceinline__ float b2f(U16 u) {
  union { unsigned int i; float f; } x; x.i = ((unsigned int)u) << 16; return x.f;
}
__device__ __forceinline__ U16 f2b(float f) {
  union { float f; unsigned int i; } x; x.f = f;
  unsigned int r = x.i + 0x7FFFu + ((x.i >> 16) & 1u);
  return (U16)(r >> 16);
}
__device__ __forceinline__ unsigned cvt_pk_bf16(float a, float b) {
  union { __hip_bfloat162 h2; unsigned u; } x;
  x.h2 = __float22bfloat162_rn(make_float2(a, b));
  return x.u;
}
__device__ __forceinline__ float fast_silu(float z) {
  return z * __builtin_amdgcn_rcpf(1.f + __expf(-z));
}
__device__ __forceinline__ void load_lds16(const U16* g, U16* l) {
  __builtin_amdgcn_global_load_lds((const __attribute__((address_space(1))) void*)g,
                                   (__attribute__((address_space(3))) void*)l, 16, 0, 0);
}

// ---------------- device-scope grid barrier (low-traffic poll) ----------------
__device__ __forceinline__ void gbar(unsigned* cnt, int idx, unsigned nb) {
  __syncthreads();
  if (threadIdx.x == 0) {
    __threadfence();  // agent release
    atomicAdd(&cnt[idx * 16], 1u);
    while (__hip_atomic_load(&cnt[idx * 16], __ATOMIC_RELAXED,
                             __HIP_MEMORY_SCOPE_AGENT) < nb)
      __builtin_amdgcn_s_sleep(32);  // ~2k cycles between polls
    __threadfence();  // agent acquire
  }
  __syncthreads();
}

// ---------------- layernorm row (shfl reduce, one barrier) ----------------
__device__ __forceinline__ void ln_row(int row, const float* __restrict__ X,
                                       const float* __restrict__ gam,
                                       const float* __restrict__ bet,
                                       U16* __restrict__ Y) {
  int tid = threadIdx.x, lane = tid & 63, wave = tid >> 6;
  __shared__ float p1[4], p2[4];
  __syncthreads();  // protect p1/p2 + caller LDS across loop iterations
  float v[3];
#pragma unroll
  for (int j = 0; j < 3; ++j) v[j] = X[(size_t)row * 768 + tid + j * 256];
  float s1 = v[0] + v[1] + v[2];
  float s2 = v[0] * v[0] + v[1] * v[1] + v[2] * v[2];
#pragma unroll
  for (int m = 32; m > 0; m >>= 1) {
    s1 += __shfl_xor(s1, m);
    s2 += __shfl_xor(s2, m);
  }
  if (lane == 0) { p1[wave] = s1; p2[wave] = s2; }
  __syncthreads();
  float t1 = p1[0] + p1[1] + p1[2] + p1[3];
  float t2 = p2[0] + p2[1] + p2[2] + p2[3];
  float mean = t1 * (1.f / 768.f);
  float var = t2 * (1.f / 768.f) - mean * mean;
  float rstd = rsqrtf(var + 1e-5f);
#pragma unroll
  for (int j = 0; j < 3; ++j) {
    int c = tid + j * 256;
    Y[(size_t)row * 768 + c] = f2b((v[j] - mean) * rstd * gam[c] + bet[c]);
  }
}

// ---------------- merged weight-prep + LN1 kernel ----------------
__global__ __launch_bounds__(256) void prep_kernel(
    const float* __restrict__ qkv_w, const float* __restrict__ out_w,
    const float* __restrict__ g1w, const float* __restrict__ g2w,
    const float* __restrict__ ff1w, const float* __restrict__ ff2w,
    const float* __restrict__ rb1w, const float* __restrict__ rb2w,
    const float* __restrict__ qkv_b, const float* __restrict__ gate_b1,
    U16* __restrict__ qkv_wT, U16* __restrict__ out_wT, U16* __restrict__ g1wT,
    U16* __restrict__ g2wT, U16* __restrict__ ff1wT, U16* __restrict__ ff2wT,
    U16* __restrict__ rb1wT, U16* __restrict__ rb2wL, float* __restrict__ qg_bias,
    const float* __restrict__ x, const float* __restrict__ ln1_g,
    const float* __restrict__ ln1_b, U16* __restrict__ xn) {
  int bid = blockIdx.x;
  if (bid >= 5868) {  // LN1
    ln_row(bid - 5868, x, ln1_g, ln1_b, xn);
    return;
  }
  if (bid >= 5856) {  // qkv_b ++ gate_b1
    int idx = (bid - 5856) * 256 + threadIdx.x;
    qg_bias[idx] = (idx < 2304) ? qkv_b[idx] : gate_b1[idx - 2304];
    return;
  }
  if (bid >= 5808) {  // rb_w2 chunk
    int idx = (bid - 5808) * 256 + threadIdx.x;
    int j = idx & 7, lane = (idx >> 3) & 63, pp = idx >> 9;
    int row = lane & 15, col = pp * 32 + ((lane >> 4) << 3) + j;
    rb2wL[idx] = (row < 12) ? f2b(rb2w[col * 12 + row]) : (U16)0;
    return;
  }
  const float* in; U16* out; int R, C, base;
  if (bid < 1728)      { in = qkv_w; out = qkv_wT; R = 768;  C = 2304; base = 0; }
  else if (bid < 2304) { in = out_w; out = out_wT; R = 768;  C = 768;  base = 1728; }
  else if (bid < 2880) { in = g1w;   out = g1wT;   R = 768;  C = 768;  base = 2304; }
  else if (bid < 3456) { in = g2w;   out = g2wT;   R = 768;  C = 768;  base = 2880; }
  else if (bid < 4608) { in = ff1w;  out = ff1wT;  R = 768;  C = 1536; base = 3456; }
  else if (bid < 5760) { in = ff2w;  out = ff2wT;  R = 1536; C = 768;  base = 4608; }
  else                 { in = rb1w;  out = rb1wT;  R = 64;   C = 768;  base = 5760; }
  int bx = bid - base, tilesx = C / 32;
  int c0 = (bx % tilesx) * 32, r0 = (bx / tilesx) * 32;
  __shared__ float tile[32][33];
  int tx = threadIdx.x & 31, ty = threadIdx.x >> 5;
#pragma unroll
  for (int yy = 0; yy < 4; ++yy)
    tile[ty + yy * 8][tx] = in[(size_t)(r0 + ty + yy * 8) * C + c0 + tx];
  __syncthreads();
#pragma unroll
  for (int yy = 0; yy < 4; ++yy)
    out[(size_t)(c0 + ty + yy * 8) * R + r0 + tx] = f2b(tile[tx][ty + yy * 8]);
}

// ---------------- double-buffered bf16-MFMA GEMM core ----------------
// EPI: 0=none 2=gelu 4=z+other(fp32 out) 5=fused qkv/gate1 6=sigmoid->bf16
template <int EPI, bool OUTF32>
__device__ void gemm_core(U16* sA, U16* sB,  // each [2*2048]
                          const U16* A, const U16* BT, const float* bias,
                          const float* other, void* Cout, float* Cout2,
                          int N, int K, int bx, int by) {
  int tid = threadIdx.x;
  int lane = tid & 63, wave = tid >> 6;
  int m0 = by * 64, n0 = bx * 64;
  int wm = (wave >> 1) * 32, wn = (wave & 1) * 32;
  int lm = lane & 15, lq = lane >> 4;
  int srow = tid >> 2, scol = (tid & 3) * 8;
  const U16* ag = A + (size_t)(m0 + srow) * K + scol;
  const U16* bg = BT + (size_t)(n0 + srow) * K + scol;
  int nit = K >> 5;
  load_lds16(ag, sA + tid * 8);
  load_lds16(bg, sB + tid * 8);
  f32x4_t acc[2][2] = {};
  for (int i = 0; i < nit; ++i) {
    __syncthreads();
    int cb = (i & 1) * 2048, nb = ((i + 1) & 1) * 2048;
    if (i + 1 < nit) {
      load_lds16(ag + (i + 1) * 32, sA + nb + tid * 8);
      load_lds16(bg + (i + 1) * 32, sB + nb + tid * 8);
    }
    Frag af[2], bf[2];
#pragma unroll
    for (int mt = 0; mt < 2; ++mt)
      af[mt].u4 = *(const uint4*)&sA[cb + (wm + mt * 16 + lm) * 32 + lq * 8];
#pragma unroll
    for (int nt = 0; nt < 2; ++nt)
      bf[nt].u4 = *(const uint4*)&sB[cb + (wn + nt * 16 + lm) * 32 + lq * 8];
#pragma unroll
    for (int mt = 0; mt < 2; ++mt)
#pragma unroll
      for (int nt = 0; nt < 2; ++nt)
        acc[mt][nt] = __builtin_amdgcn_mfma_f32_16x16x32_bf16(af[mt].b8, bf[nt].b8,
                                                              acc[mt][nt], 0, 0, 0);
  }
#pragma unroll
  for (int nt = 0; nt < 2; ++nt) {
    int gc = n0 + wn + nt * 16 + lm;
    float bz = bias[gc];
#pragma unroll
    for (int mt = 0; mt < 2; ++mt) {
#pragma unroll
      for (int r = 0; r < 4; ++r) {
        int gr = m0 + wm + mt * 16 + lq * 4 + r;
        float z = acc[mt][nt][r] + bz;
        if (EPI == 5) {
          if (gc < 2304) Cout2[(size_t)gr * 2304 + gc] = z;
          else ((U16*)Cout)[(size_t)gr * 768 + gc - 2304] = f2b(fast_silu(z));
          continue;
        }
        size_t idx = (size_t)gr * N + gc;
        float o;
        if (EPI == 0) o = z;
        else if (EPI == 2) o = 0.5f * z * (1.f + erff(z * 0.70710678118f));
        else if (EPI == 6) o = __builtin_amdgcn_rcpf(1.f + __expf(-z));
        else o = z + other[idx];
        if (OUTF32) ((float*)Cout)[idx] = o;
        else ((U16*)Cout)[idx] = f2b(o);
      }
    }
  }
}

// ---------------- relative-bias MLP body (512 rows; verified R3-R11) ----------------
__device__ void rb_body(int bid, const float* dist, const U16* w1T, const float* b1,
                        const U16* w2L, const float* b2, float* biasOut) {
  int tid = threadIdx.x;
  int lane = tid & 63, wave = tid >> 6;
  int lm = lane & 15, lq = lane >> 4;
  int r0 = bid * 512;
  float hb = (lm < 12) ? b2[lm] : 0.f;
  Frag bd[8][2];
#pragma unroll
  for (int g = 0; g < 8; ++g) {
    const float* ap = dist + (size_t)(r0 + (wave * 8 + g) * 16 + lm) * 64 + lq * 8;
    float4 v0 = ((const float4*)ap)[0];
    float4 v1 = ((const float4*)ap)[1];
    float4 v2 = ((const float4*)(ap + 32))[0];
    float4 v3 = ((const float4*)(ap + 32))[1];
    bd[g][0].u[0] = cvt_pk_bf16(v0.x, v0.y); bd[g][0].u[1] = cvt_pk_bf16(v0.z, v0.w);
    bd[g][0].u[2] = cvt_pk_bf16(v1.x, v1.y); bd[g][0].u[3] = cvt_pk_bf16(v1.z, v1.w);
    bd[g][1].u[0] = cvt_pk_bf16(v2.x, v2.y); bd[g][1].u[1] = cvt_pk_bf16(v2.z, v2.w);
    bd[g][1].u[2] = cvt_pk_bf16(v3.x, v3.y); bd[g][1].u[3] = cvt_pk_bf16(v3.z, v3.w);
  }
  const U16* w1p0 = w1T + (size_t)(((lm >> 2) << 3) + (lm & 3)) * 64 + lq * 8;
  const U16* w1p1 = w1p0 + 256;
  const U16* w2p = w2L + lane * 8;
  const float* b1p = b1 + lq * 8;
  f32x4_t bacc[8];
#pragma unroll
  for (int g = 0; g < 8; ++g) bacc[g] = {hb, hb, hb, hb};

  auto loadw = [&](int j, Frag& f00, Frag& f01, Frag& f10, Frag& f11, Frag& fwb,
                   float4& fb0, float4& fb1) {
    const U16* p0 = w1p0 + (size_t)j * 2048;
    const U16* p1 = w1p1 + (size_t)j * 2048;
    f00.u4 = *(const uint4*)p0;
    f01.u4 = *(const uint4*)(p0 + 32);
    f10.u4 = *(const uint4*)p1;
    f11.u4 = *(const uint4*)(p1 + 32);
    fwb.u4 = *(const uint4*)(w2p + (size_t)j * 512);
    fb0 = *(const float4*)(b1p + j * 32);
    fb1 = *(const float4*)(b1p + j * 32 + 4);
  };
  auto comp = [&](Frag& f00, Frag& f01, Frag& f10, Frag& f11, Frag& fwb,
                  float4 fb0, float4 fb1) {
    f32x4_t cz0 = {fb0.x, fb0.y, fb0.z, fb0.w};
    f32x4_t cz1 = {fb1.x, fb1.y, fb1.z, fb1.w};
#pragma unroll
    for (int g = 0; g < 8; ++g) {
      f32x4_t z0 = cz0, z1 = cz1;
      z0 = __builtin_amdgcn_mfma_f32_16x16x32_bf16(f00.b8, bd[g][0].b8, z0, 0, 0, 0);
      z0 = __builtin_amdgcn_mfma_f32_16x16x32_bf16(f01.b8, bd[g][1].b8, z0, 0, 0, 0);
      z1 = __builtin_amdgcn_mfma_f32_16x16x32_bf16(f10.b8, bd[g][0].b8, z1, 0, 0, 0);
      z1 = __builtin_amdgcn_mfma_f32_16x16x32_bf16(f11.b8, bd[g][1].b8, z1, 0, 0, 0);
      float s0 = fast_silu(z0[0]), s1 = fast_silu(z0[1]);
      float s2 = fast_silu(z0[2]), s3 = fast_silu(z0[3]);
      float t0 = fast_silu(z1[0]), t1 = fast_silu(z1[1]);
      float t2 = fast_silu(z1[2]), t3 = fast_silu(z1[3]);
      Frag af2;
      af2.u[0] = cvt_pk_bf16(s0, s1); af2.u[1] = cvt_pk_bf16(s2, s3);
      af2.u[2] = cvt_pk_bf16(t0, t1); af2.u[3] = cvt_pk_bf16(t2, t3);
      bacc[g] = __builtin_amdgcn_mfma_f32_16x16x32_bf16(af2.b8, fwb.b8, bacc[g], 0, 0, 0);
    }
  };

  Frag e00, e01, e10, e11, ewb, o00, o01, o10, o11, owb;
  float4 eb0, eb1, ob0, ob1;
  loadw(0, e00, e01, e10, e11, ewb, eb0, eb1);
  for (int pp = 0; pp < 24; pp += 2) {
    loadw(pp + 1, o00, o01, o10, o11, owb, ob0, ob1);
    comp(e00, e01, e10, e11, ewb, eb0, eb1);
    if (pp + 2 < 24) loadw(pp + 2, e00, e01, e10, e11, ewb, eb0, eb1);
    comp(o00, o01, o10, o11, owb, ob0, ob1);
  }
  if (lm < 12) {
#pragma unroll
    for (int g = 0; g < 8; ++g) {
#pragma unroll
      for (int r = 0; r < 4; ++r) {
        int gr = r0 + (wave * 8 + g) * 16 + lq * 4 + r;
        int b = gr >> 16, rem = gr & 65535, i = rem >> 8, j = rem & 255;
        biasOut[(((size_t)b * 12 + lm) * 256 + i) * 256 + j] = bacc[g][r];
      }
    }
  }
}

// ---------------- merged launch: rb (0..511) + qkv/gate1 GEMM (512..1279) ----
__global__ __launch_bounds__(256) void qkvrb_kernel(
    const U16* __restrict__ xn, const U16* __restrict__ qg_wT,
    const float* __restrict__ qg_b, float* __restrict__ qkvb, U16* __restrict__ g1,
    const float* __restrict__ dist, const U16* __restrict__ rb1wT,
    const float* __restrict__ rb_b1, const U16* __restrict__ rb2wL,
    const float* __restrict__ rb_b2, float* __restrict__ biasB) {
  __shared__ __align__(16) U16 sA[2 * 2048];
  __shared__ __align__(16) U16 sB[2 * 2048];
  int bid = blockIdx.x;
  if (bid < 512) {
    rb_body(bid, dist, rb1wT, rb_b1, rb2wL, rb_b2, biasB);
  } else {
    int g = bid - 512;
    gemm_core<5, false>(sA, sB, xn, qg_wT, qg_b, nullptr, g1, qkvb, 3072, 768,
                        g % 48, g / 48);
  }
}

// ---------------- attention body (in-LDS K transpose; verified R8-R11) ----------------
__device__ void attn_body(unsigned char* smem, int bid, const float* qkv,
                          const float* biasB, const int* mask, float* ctx) {
  U16* sK = (U16*)smem;                          // 64*258*2 = 33024 B
  float(*sQ)[66] = (float(*)[66])(smem + 33024); // 16*66*4 = 4224 B
  float* sP = (float*)(smem + 33024 + 4224);     // 16*256*4 = 16384 B
  int tid = threadIdx.x, lane = tid & 63, w = tid >> 6;
  int bh = bid >> 4, b = bh / 12, h = bh % 12;
  int i0 = (bid & 15) * 16;
  {
    int r = tid >> 4, c = (tid & 15) * 4;
    *(float4*)&sQ[r][c] =
        *(const float4*)&qkv[((size_t)(b * 256 + i0 + r)) * 2304 + h * 64 + c];
  }
  {
    const float* kr = qkv + ((size_t)(b * 256 + w * 64)) * 2304 + 768 + h * 64 + lane;
#pragma unroll 8
    for (int rr = 0; rr < 64; ++rr) {
      float kv = kr[(size_t)rr * 2304];
      sK[lane * 258 + w * 64 + rr] = (U16)cvt_pk_bf16(kv, kv);
    }
  }
  __syncthreads();
  int iw = i0 + w * 4;
  float lacc[4][4] = {};
#pragma unroll 4
  for (int d = 0; d < 64; ++d) {
    float k0 = b2f(sK[d * 258 + lane]);
    float k1 = b2f(sK[d * 258 + 64 + lane]);
    float k2 = b2f(sK[d * 258 + 128 + lane]);
    float k3 = b2f(sK[d * 258 + 192 + lane]);
#pragma unroll
    for (int qi = 0; qi < 4; ++qi) {
      float qv = sQ[w * 4 + qi][d];
      lacc[qi][0] += qv * k0;
      lacc[qi][1] += qv * k1;
      lacc[qi][2] += qv * k2;
      lacc[qi][3] += qv * k3;
    }
  }
#pragma unroll
  for (int qi = 0; qi < 4; ++qi) {
    int gi = iw + qi;
    const float* brow = biasB + (((size_t)b * 12 + h) * 256 + gi) * 256;
    const int* mrow = mask + ((size_t)b * 256 + gi) * 256;
    float lg[4];
#pragma unroll
    for (int jc = 0; jc < 4; ++jc) {
      float lv = lacc[qi][jc] * 0.125f + brow[jc * 64 + lane];
      lg[jc] = mrow[jc * 64 + lane] ? lv : -1e30f;
    }
    float mx = fmaxf(fmaxf(lg[0], lg[1]), fmaxf(lg[2], lg[3]));
#pragma unroll
    for (int m = 32; m > 0; m >>= 1) mx = fmaxf(mx, __shfl_xor(mx, m));
    float e[4], sum = 0.f;
#pragma unroll
    for (int jc = 0; jc < 4; ++jc) { e[jc] = __expf(lg[jc] - mx); sum += e[jc]; }
#pragma unroll
    for (int m = 32; m > 0; m >>= 1) sum += __shfl_xor(sum, m);
    float inv = __builtin_amdgcn_rcpf(sum);
#pragma unroll
    for (int jc = 0; jc < 4; ++jc) sP[(w * 4 + qi) * 256 + jc * 64 + lane] = e[jc] * inv;
  }
  float ca[4] = {0.f, 0.f, 0.f, 0.f};
  const float* vcol = qkv + (size_t)b * 256 * 2304 + 1536 + h * 64 + lane;
#pragma unroll 2
  for (int j4 = 0; j4 < 256; j4 += 4) {
    float4 p0 = *(const float4*)&sP[(w * 4 + 0) * 256 + j4];
    float4 p1 = *(const float4*)&sP[(w * 4 + 1) * 256 + j4];
    float4 p2 = *(const float4*)&sP[(w * 4 + 2) * 256 + j4];
    float4 p3 = *(const float4*)&sP[(w * 4 + 3) * 256 + j4];
    const float* pp0 = (const float*)&p0;
    const float* pp1 = (const float*)&p1;
    const float* pp2 = (const float*)&p2;
    const float* pp3 = (const float*)&p3;
#pragma unroll
    for (int jj = 0; jj < 4; ++jj) {
      float v = vcol[(size_t)(j4 + jj) * 2304];
      ca[0] += pp0[jj] * v;
      ca[1] += pp1[jj] * v;
      ca[2] += pp2[jj] * v;
      ca[3] += pp3[jj] * v;
    }
  }
#pragma unroll
  for (int qi = 0; qi < 4; ++qi)
    ctx[((size_t)(b * 256 + iw + qi)) * 768 + h * 64 + lane] = ca[qi];
}

// ---------------- merged: attention (0..767) + gate2' sigmoid GEMM (768..959) ----------------
__global__ __launch_bounds__(256) void attn_gate_kernel(
    const float* __restrict__ qkv, const float* __restrict__ biasB,
    const int* __restrict__ mask, float* __restrict__ ctx,
    const U16* __restrict__ g1, const U16* __restrict__ g2wT,
    const float* __restrict__ gate_b2, U16* __restrict__ sg) {
  __shared__ __align__(16) unsigned char smem[53632];
  int bid = blockIdx.x;
  if (bid < 768) {
    attn_body(smem, bid, qkv, biasB, mask, ctx);
  } else {
    int g = bid - 768;
    gemm_core<6, false>((U16*)smem, (U16*)(smem + 8192), g1, g2wT, gate_b2, nullptr,
                        sg, nullptr, 768, 768, g % 12, g / 12);
  }
}

// ---------------- out-projection body: x2 = (ctx .* sg) @ out_w + out_b + x ----------------
__device__ void outp_body(U16* sA, U16* sB, int bx, int by, const float* ctx,
                          const U16* sg, const U16* out_wT, const float* out_b,
                          const float* x, float* x2) {
  int tid = threadIdx.x;
  int lane = tid & 63, wave = tid >> 6;
  int m0 = by * 64, n0 = bx * 64;
  int wm = (wave >> 1) * 32, wn = (wave & 1) * 32;
  int lm = lane & 15, lq = lane >> 4;
  int srow = tid >> 2, scol = (tid & 3) * 8;
  const float* cg0 = ctx + (size_t)(m0 + srow) * 768 + scol;
  const U16* sg0 = sg + (size_t)(m0 + srow) * 768 + scol;
  const U16* bg = out_wT + (size_t)(n0 + srow) * 768 + scol;
  load_lds16(bg, sB + tid * 8);
  float4 ca0 = *(const float4*)cg0;
  float4 ca1 = *(const float4*)(cg0 + 4);
  Frag sa; sa.u4 = *(const uint4*)sg0;
  f32x4_t acc[2][2] = {};
  for (int i = 0; i < 24; ++i) {
    __syncthreads();
    int cb = (i & 1) * 2048, nb = ((i + 1) & 1) * 2048;
    if (i + 1 < 24) load_lds16(bg + (i + 1) * 32, sB + nb + tid * 8);
    Frag av;
    av.u[0] = cvt_pk_bf16(ca0.x * b2f(sa.s[0]), ca0.y * b2f(sa.s[1]));
    av.u[1] = cvt_pk_bf16(ca0.z * b2f(sa.s[2]), ca0.w * b2f(sa.s[3]));
    av.u[2] = cvt_pk_bf16(ca1.x * b2f(sa.s[4]), ca1.y * b2f(sa.s[5]));
    av.u[3] = cvt_pk_bf16(ca1.z * b2f(sa.s[6]), ca1.w * b2f(sa.s[7]));
    *(uint4*)&sA[tid * 8] = av.u4;
    if (i + 1 < 24) {
      ca0 = *(const float4*)(cg0 + (i + 1) * 32);
      ca1 = *(const float4*)(cg0 + (i + 1) * 32 + 4);
      sa.u4 = *(const uint4*)(sg0 + (i + 1) * 32);
    }
    __syncthreads();
    Frag af[2], bf[2];
#pragma unroll
    for (int mt = 0; mt < 2; ++mt)
      af[mt].u4 = *(const uint4*)&sA[(wm + mt * 16 + lm) * 32 + lq * 8];
#pragma unroll
    for (int nt = 0; nt < 2; ++nt)
      bf[nt].u4 = *(const uint4*)&sB[cb + (wn + nt * 16 + lm) * 32 + lq * 8];
#pragma unroll
    for (int mt = 0; mt < 2; ++mt)
#pragma unroll
      for (int nt = 0; nt < 2; ++nt)
        acc[mt][nt] = __builtin_amdgcn_mfma_f32_16x16x32_bf16(af[mt].b8, bf[nt].b8,
                                                              acc[mt][nt], 0, 0, 0);
  }
#pragma unroll
  for (int nt = 0; nt < 2; ++nt) {
    int gc = n0 + wn + nt * 16 + lm;
    float bz = out_b[gc];
#pragma unroll
    for (int mt = 0; mt < 2; ++mt) {
#pragma unroll
      for (int r = 0; r < 4; ++r) {
        int gr = m0 + wm + mt * 16 + lq * 4 + r;
        size_t idx = (size_t)gr * 768 + gc;
        x2[idx] = acc[mt][nt][r] + bz + x[idx];
      }
    }
  }
}

// ---------------- tail megakernel: outp -> LN2 -> FF1 -> FF2, 3 grid barriers ----------------
// 384 blocks, 16 KB LDS, launch_bounds(256,2) => capacity 512 blocks, co-residency guaranteed.
__global__ __launch_bounds__(256, 2) void tail_kernel(
    const float* ctx, const U16* sg, const U16* out_wT, const float* out_b,
    const float* x, float* x2, const float* ln2_g, const float* ln2_b, U16* y,
    const U16* ff1wT, const float* ff_b1, U16* f1, const U16* ff2wT,
    const float* ff_b2, float* dout, unsigned* counters) {
  __shared__ __align__(16) U16 sA[2 * 2048];
  __shared__ __align__(16) U16 sB[2 * 2048];
  const unsigned NB = 384;
  // P0: out-projection with on-the-fly gating + residual (192 tiles)
  for (int it = blockIdx.x; it < 192; it += NB)
    outp_body(sA, sB, it % 12, it / 12, ctx, sg, out_wT, out_b, x, x2);
  gbar(counters, 0, NB);
  // P1: LN2 (1024 rows)
  for (int it = blockIdx.x; it < 1024; it += NB)
    ln_row(it, x2, ln2_g, ln2_b, y);
  gbar(counters, 1, NB);
  // P2: FF1 gelu (384 tiles)
  for (int it = blockIdx.x; it < 384; it += NB)
    gemm_core<2, false>(sA, sB, y, ff1wT, ff_b1, nullptr, f1, nullptr,
                        1536, 768, it % 24, it / 24);
  gbar(counters, 2, NB);
  // P3: FF2 + residual -> out (192 tiles)
  for (int it = blockIdx.x; it < 192; it += NB)
    gemm_core<4, true>(sA, sB, f1, ff2wT, ff_b2, x2, dout, nullptr,
                       768, 1536, it % 12, it / 12);
}

// ---------------- launcher ----------------
extern "C" void kernel_launch(void* const* d_in, const int* in_sizes, int n_in,
                              void* d_out, int out_size, void* d_ws, size_t ws_size,
                              hipStream_t stream) {
  const float* x       = (const float*)d_in[0];
  const float* dist    = (const float*)d_in[1];
  const int* mask      = (const int*)d_in[2];
  const float* qkv_w   = (const float*)d_in[3];
  const float* qkv_b   = (const float*)d_in[4];
  const float* out_w   = (const float*)d_in[5];
  const float* out_b   = (const float*)d_in[6];
  const float* rb_w1   = (const float*)d_in[7];
  const float* rb_b1   = (const float*)d_in[8];
  const float* rb_w2   = (const float*)d_in[9];
  const float* rb_b2   = (const float*)d_in[10];
  const float* gate_w1 = (const float*)d_in[11];
  const float* gate_b1 = (const float*)d_in[12];
  const float* gate_w2 = (const float*)d_in[13];
  const float* gate_b2 = (const float*)d_in[14];
  const float* ff_w1   = (const float*)d_in[15];
  const float* ff_b1   = (const float*)d_in[16];
  const float* ff_w2   = (const float*)d_in[17];
  const float* ff_b2   = (const float*)d_in[18];
  const float* ln1_g   = (const float*)d_in[19];
  const float* ln1_b   = (const float*)d_in[20];
  const float* ln2_g   = (const float*)d_in[21];
  const float* ln2_b   = (const float*)d_in[22];

  char* w = (char*)d_ws;
  auto alloc = [&](size_t bytes) {
    char* p = w;
    w += (bytes + 255) & ~(size_t)255;
    return p;
  };
  unsigned* counters = (unsigned*)alloc(512);
  U16* xn      = (U16*)alloc(1024 * 768 * 2);
  float* qkvb  = (float*)alloc((size_t)1024 * 2304 * 4);
  U16* qg_wT   = (U16*)alloc((size_t)3072 * 768 * 2);
  U16* qkv_wT  = qg_wT;
  U16* g1wT    = qg_wT + (size_t)2304 * 768;
  float* qg_b  = (float*)alloc(3072 * 4);
  U16* out_wT  = (U16*)alloc(768 * 768 * 2);
  U16* g2wT    = (U16*)alloc(768 * 768 * 2);
  U16* ff1wT   = (U16*)alloc(1536 * 768 * 2);
  U16* ff2wT   = (U16*)alloc(768 * 1536 * 2);
  U16* rb1wT   = (U16*)alloc(768 * 64 * 2);
  U16* rb2wL   = (U16*)alloc(24 * 64 * 8 * 2);
  float* biasB = (float*)alloc((size_t)4 * 12 * 256 * 256 * 4);
  float* ctx   = (float*)alloc(1024 * 768 * 4);
  U16* g1      = (U16*)alloc(1024 * 768 * 2);
  U16* sg      = (U16*)alloc(1024 * 768 * 2);
  float* x2    = (float*)alloc(1024 * 768 * 4);
  U16* y       = (U16*)alloc(1024 * 768 * 2);
  U16* f1      = (U16*)alloc(1024 * 1536 * 2);
  (void)ws_size; (void)in_sizes; (void)n_in; (void)out_size;

  hipMemsetAsync(counters, 0, 512, stream);
  // 1: weight prep + LN1
  prep_kernel<<<6892, 256, 0, stream>>>(qkv_w, out_w, gate_w1, gate_w2, ff_w1, ff_w2,
                                        rb_w1, rb_w2, qkv_b, gate_b1,
                                        qkv_wT, out_wT, g1wT, g2wT, ff1wT, ff2wT,
                                        rb1wT, rb2wL, qg_b, x, ln1_g, ln1_b, xn);
  // 2: rb bias MLP (512, first) + fused qkv/gate1 GEMM (768)
  qkvrb_kernel<<<1280, 256, 0, stream>>>(xn, qg_wT, qg_b, qkvb, g1,
                                         dist, rb1wT, rb_b1, rb2wL, rb_b2, biasB);
  // 3: attention + gate2' (sg = sigmoid(g1@g2w+b))
  attn_gate_kernel<<<960, 256, 0, stream>>>(qkvb, biasB, mask, ctx,
                                            g1, g2wT, gate_b2, sg);
  // 4: tail megakernel (outp -> LN2 -> FF1 -> FF2)
  tail_kernel<<<384, 256, 0, stream>>>(ctx, sg, out_wT, out_b, x, x2, ln2_g, ln2_b,
                                       y, ff1wT, ff_b1, f1, ff2wT, ff_b2,
                                       (float*)d_out, counters);
}

// Round 13
// 314.895 us; speedup vs baseline: 1.9469x; 1.3524x over previous
//
#include <hip/hip_runtime.h>
#include <hip/hip_bf16.h>
#include <cmath>

#define U16 unsigned short

typedef __bf16 bf16x8_t __attribute__((ext_vector_type(8)));
typedef float f32x4_t __attribute__((ext_vector_type(4)));

union Frag { uint4 u4; unsigned u[4]; bf16x8_t b8; U16 s[8]; };

__device__ __forceinline__ float b2f(U16 u) {
  union { unsigned int i; float f; } x; x.i = ((unsigned int)u) << 16; return x.f;
}
__device__ __forceinline__ U16 f2b(float f) {
  union { float f; unsigned int i; } x; x.f = f;
  unsigned int r = x.i + 0x7FFFu + ((x.i >> 16) & 1u);
  return (U16)(r >> 16);
}
__device__ __forceinline__ unsigned cvt_pk_bf16(float a, float b) {
  union { __hip_bfloat162 h2; unsigned u; } x;
  x.h2 = __float22bfloat162_rn(make_float2(a, b));
  return x.u;
}
__device__ __forceinline__ float fast_silu(float z) {
  return z * __builtin_amdgcn_rcpf(1.f + __expf(-z));
}
__device__ __forceinline__ void load_lds16(const U16* g, U16* l) {
  __builtin_amdgcn_global_load_lds((const __attribute__((address_space(1))) void*)g,
                                   (__attribute__((address_space(3))) void*)l, 16, 0, 0);
}

// ---------------- layernorm row (shfl reduce, one barrier) ----------------
__device__ __forceinline__ void ln_row(int row, const float* __restrict__ X,
                                       const float* __restrict__ gam,
                                       const float* __restrict__ bet,
                                       U16* __restrict__ Y) {
  int tid = threadIdx.x, lane = tid & 63, wave = tid >> 6;
  __shared__ float p1[4], p2[4];
  float v[3];
#pragma unroll
  for (int j = 0; j < 3; ++j) v[j] = X[(size_t)row * 768 + tid + j * 256];
  float s1 = v[0] + v[1] + v[2];
  float s2 = v[0] * v[0] + v[1] * v[1] + v[2] * v[2];
#pragma unroll
  for (int m = 32; m > 0; m >>= 1) {
    s1 += __shfl_xor(s1, m);
    s2 += __shfl_xor(s2, m);
  }
  if (lane == 0) { p1[wave] = s1; p2[wave] = s2; }
  __syncthreads();
  float t1 = p1[0] + p1[1] + p1[2] + p1[3];
  float t2 = p2[0] + p2[1] + p2[2] + p2[3];
  float mean = t1 * (1.f / 768.f);
  float var = t2 * (1.f / 768.f) - mean * mean;
  float rstd = rsqrtf(var + 1e-5f);
#pragma unroll
  for (int j = 0; j < 3; ++j) {
    int c = tid + j * 256;
    Y[(size_t)row * 768 + c] = f2b((v[j] - mean) * rstd * gam[c] + bet[c]);
  }
}

// ---------------- merged weight-prep + LN1 kernel ----------------
__global__ __launch_bounds__(256) void prep_kernel(
    const float* __restrict__ qkv_w, const float* __restrict__ out_w,
    const float* __restrict__ g1w, const float* __restrict__ g2w,
    const float* __restrict__ ff1w, const float* __restrict__ ff2w,
    const float* __restrict__ rb1w, const float* __restrict__ rb2w,
    const float* __restrict__ qkv_b, const float* __restrict__ gate_b1,
    U16* __restrict__ qkv_wT, U16* __restrict__ out_wT, U16* __restrict__ g1wT,
    U16* __restrict__ g2wT, U16* __restrict__ ff1wT, U16* __restrict__ ff2wT,
    U16* __restrict__ rb1wT, U16* __restrict__ rb2wL, float* __restrict__ qg_bias,
    const float* __restrict__ x, const float* __restrict__ ln1_g,
    const float* __restrict__ ln1_b, U16* __restrict__ xn) {
  int bid = blockIdx.x;
  if (bid >= 5868) {  // LN1
    ln_row(bid - 5868, x, ln1_g, ln1_b, xn);
    return;
  }
  if (bid >= 5856) {  // qkv_b ++ gate_b1
    int idx = (bid - 5856) * 256 + threadIdx.x;
    qg_bias[idx] = (idx < 2304) ? qkv_b[idx] : gate_b1[idx - 2304];
    return;
  }
  if (bid >= 5808) {  // rb_w2 chunk
    int idx = (bid - 5808) * 256 + threadIdx.x;
    int j = idx & 7, lane = (idx >> 3) & 63, pp = idx >> 9;
    int row = lane & 15, col = pp * 32 + ((lane >> 4) << 3) + j;
    rb2wL[idx] = (row < 12) ? f2b(rb2w[col * 12 + row]) : (U16)0;
    return;
  }
  const float* in; U16* out; int R, C, base;
  if (bid < 1728)      { in = qkv_w; out = qkv_wT; R = 768;  C = 2304; base = 0; }
  else if (bid < 2304) { in = out_w; out = out_wT; R = 768;  C = 768;  base = 1728; }
  else if (bid < 2880) { in = g1w;   out = g1wT;   R = 768;  C = 768;  base = 2304; }
  else if (bid < 3456) { in = g2w;   out = g2wT;   R = 768;  C = 768;  base = 2880; }
  else if (bid < 4608) { in = ff1w;  out = ff1wT;  R = 768;  C = 1536; base = 3456; }
  else if (bid < 5760) { in = ff2w;  out = ff2wT;  R = 1536; C = 768;  base = 4608; }
  else                 { in = rb1w;  out = rb1wT;  R = 64;   C = 768;  base = 5760; }
  int bx = bid - base, tilesx = C / 32;
  int c0 = (bx % tilesx) * 32, r0 = (bx / tilesx) * 32;
  __shared__ float tile[32][33];
  int tx = threadIdx.x & 31, ty = threadIdx.x >> 5;
#pragma unroll
  for (int yy = 0; yy < 4; ++yy)
    tile[ty + yy * 8][tx] = in[(size_t)(r0 + ty + yy * 8) * C + c0 + tx];
  __syncthreads();
#pragma unroll
  for (int yy = 0; yy < 4; ++yy)
    out[(size_t)(c0 + ty + yy * 8) * R + r0 + tx] = f2b(tile[tx][ty + yy * 8]);
}

// ---------------- 64x64 double-buffered GEMM core (used by qkvrb) ----------------
// EPI: 5=fused qkv/gate1
template <int EPI, bool OUTF32>
__device__ void gemm_core(U16* sA, U16* sB,  // each [2*2048]
                          const U16* A, const U16* BT, const float* bias,
                          const float* other, void* Cout, float* Cout2,
                          int N, int K, int bx, int by) {
  int tid = threadIdx.x;
  int lane = tid & 63, wave = tid >> 6;
  int m0 = by * 64, n0 = bx * 64;
  int wm = (wave >> 1) * 32, wn = (wave & 1) * 32;
  int lm = lane & 15, lq = lane >> 4;
  int srow = tid >> 2, scol = (tid & 3) * 8;
  const U16* ag = A + (size_t)(m0 + srow) * K + scol;
  const U16* bg = BT + (size_t)(n0 + srow) * K + scol;
  int nit = K >> 5;
  load_lds16(ag, sA + tid * 8);
  load_lds16(bg, sB + tid * 8);
  f32x4_t acc[2][2] = {};
  for (int i = 0; i < nit; ++i) {
    __syncthreads();
    int cb = (i & 1) * 2048, nb = ((i + 1) & 1) * 2048;
    if (i + 1 < nit) {
      load_lds16(ag + (i + 1) * 32, sA + nb + tid * 8);
      load_lds16(bg + (i + 1) * 32, sB + nb + tid * 8);
    }
    Frag af[2], bf[2];
#pragma unroll
    for (int mt = 0; mt < 2; ++mt)
      af[mt].u4 = *(const uint4*)&sA[cb + (wm + mt * 16 + lm) * 32 + lq * 8];
#pragma unroll
    for (int nt = 0; nt < 2; ++nt)
      bf[nt].u4 = *(const uint4*)&sB[cb + (wn + nt * 16 + lm) * 32 + lq * 8];
#pragma unroll
    for (int mt = 0; mt < 2; ++mt)
#pragma unroll
      for (int nt = 0; nt < 2; ++nt)
        acc[mt][nt] = __builtin_amdgcn_mfma_f32_16x16x32_bf16(af[mt].b8, bf[nt].b8,
                                                              acc[mt][nt], 0, 0, 0);
  }
#pragma unroll
  for (int nt = 0; nt < 2; ++nt) {
    int gc = n0 + wn + nt * 16 + lm;
    float bz = bias[gc];
#pragma unroll
    for (int mt = 0; mt < 2; ++mt) {
#pragma unroll
      for (int r = 0; r < 4; ++r) {
        int gr = m0 + wm + mt * 16 + lq * 4 + r;
        float z = acc[mt][nt][r] + bz;
        if (EPI == 5) {
          if (gc < 2304) Cout2[(size_t)gr * 2304 + gc] = z;
          else ((U16*)Cout)[(size_t)gr * 768 + gc - 2304] = f2b(fast_silu(z));
          continue;
        }
        size_t idx = (size_t)gr * N + gc;
        if (OUTF32) ((float*)Cout)[idx] = z;
        else ((U16*)Cout)[idx] = f2b(z);
      }
    }
  }
}

// ---------------- 32x64 double-buffered GEMM core (tail: high block count) ----------------
// 4 waves as 2(m)x2(n); each wave 16x32 = 2 MFMAs/iter. sA 2*1024, sB 2*2048.
// EPI: 2=gelu 4=z+other(fp32 out) 6=sigmoid->bf16
template <int EPI, bool OUTF32>
__device__ void gemm32_core(U16* sA, U16* sB,
                            const U16* A, const U16* BT, const float* bias,
                            const float* other, void* Cout,
                            int N, int K, int bx, int by) {
  int tid = threadIdx.x;
  int lane = tid & 63, wave = tid >> 6;
  int m0 = by * 32, n0 = bx * 64;
  int wm = (wave >> 1) * 16, wn = (wave & 1) * 32;
  int lm = lane & 15, lq = lane >> 4;
  int srow = tid >> 2, scol = (tid & 3) * 8;
  const U16* ag = A + (size_t)(m0 + srow) * K + scol;  // valid for tid<128
  const U16* bg = BT + (size_t)(n0 + srow) * K + scol;
  int nit = K >> 5;
  if (tid < 128) load_lds16(ag, sA + tid * 8);
  load_lds16(bg, sB + tid * 8);
  f32x4_t acc[2] = {};
  for (int i = 0; i < nit; ++i) {
    __syncthreads();
    int cbA = (i & 1) * 1024, nbA = ((i + 1) & 1) * 1024;
    int cbB = (i & 1) * 2048, nbB = ((i + 1) & 1) * 2048;
    if (i + 1 < nit) {
      if (tid < 128) load_lds16(ag + (i + 1) * 32, sA + nbA + tid * 8);
      load_lds16(bg + (i + 1) * 32, sB + nbB + tid * 8);
    }
    Frag af, bf[2];
    af.u4 = *(const uint4*)&sA[cbA + (wm + lm) * 32 + lq * 8];
#pragma unroll
    for (int nt = 0; nt < 2; ++nt)
      bf[nt].u4 = *(const uint4*)&sB[cbB + (wn + nt * 16 + lm) * 32 + lq * 8];
#pragma unroll
    for (int nt = 0; nt < 2; ++nt)
      acc[nt] = __builtin_amdgcn_mfma_f32_16x16x32_bf16(af.b8, bf[nt].b8,
                                                        acc[nt], 0, 0, 0);
  }
#pragma unroll
  for (int nt = 0; nt < 2; ++nt) {
    int gc = n0 + wn + nt * 16 + lm;
    float bz = bias[gc];
#pragma unroll
    for (int r = 0; r < 4; ++r) {
      int gr = m0 + wm + lq * 4 + r;
      size_t idx = (size_t)gr * N + gc;
      float z = acc[nt][r] + bz;
      float o;
      if (EPI == 2) o = 0.5f * z * (1.f + erff(z * 0.70710678118f));
      else if (EPI == 6) o = __builtin_amdgcn_rcpf(1.f + __expf(-z));
      else o = z + other[idx];
      if (OUTF32) ((float*)Cout)[idx] = o;
      else ((U16*)Cout)[idx] = f2b(o);
    }
  }
}

template <int EPI, bool OUTF32>
__global__ __launch_bounds__(256) void gemm32_bt(const U16* __restrict__ A,
                                                 const U16* __restrict__ BT,
                                                 const float* __restrict__ bias,
                                                 const float* __restrict__ other,
                                                 void* __restrict__ Cout,
                                                 int N, int K) {
  __shared__ __align__(16) U16 sA[2 * 1024];
  __shared__ __align__(16) U16 sB[2 * 2048];
  gemm32_core<EPI, OUTF32>(sA, sB, A, BT, bias, other, Cout, N, K,
                           blockIdx.x, blockIdx.y);
}

// ---------------- relative-bias MLP body (512 rows; verified R3-R12) ----------------
__device__ void rb_body(int bid, const float* dist, const U16* w1T, const float* b1,
                        const U16* w2L, const float* b2, float* biasOut) {
  int tid = threadIdx.x;
  int lane = tid & 63, wave = tid >> 6;
  int lm = lane & 15, lq = lane >> 4;
  int r0 = bid * 512;
  float hb = (lm < 12) ? b2[lm] : 0.f;
  Frag bd[8][2];
#pragma unroll
  for (int g = 0; g < 8; ++g) {
    const float* ap = dist + (size_t)(r0 + (wave * 8 + g) * 16 + lm) * 64 + lq * 8;
    float4 v0 = ((const float4*)ap)[0];
    float4 v1 = ((const float4*)ap)[1];
    float4 v2 = ((const float4*)(ap + 32))[0];
    float4 v3 = ((const float4*)(ap + 32))[1];
    bd[g][0].u[0] = cvt_pk_bf16(v0.x, v0.y); bd[g][0].u[1] = cvt_pk_bf16(v0.z, v0.w);
    bd[g][0].u[2] = cvt_pk_bf16(v1.x, v1.y); bd[g][0].u[3] = cvt_pk_bf16(v1.z, v1.w);
    bd[g][1].u[0] = cvt_pk_bf16(v2.x, v2.y); bd[g][1].u[1] = cvt_pk_bf16(v2.z, v2.w);
    bd[g][1].u[2] = cvt_pk_bf16(v3.x, v3.y); bd[g][1].u[3] = cvt_pk_bf16(v3.z, v3.w);
  }
  const U16* w1p0 = w1T + (size_t)(((lm >> 2) << 3) + (lm & 3)) * 64 + lq * 8;
  const U16* w1p1 = w1p0 + 256;
  const U16* w2p = w2L + lane * 8;
  const float* b1p = b1 + lq * 8;
  f32x4_t bacc[8];
#pragma unroll
  for (int g = 0; g < 8; ++g) bacc[g] = {hb, hb, hb, hb};

  auto loadw = [&](int j, Frag& f00, Frag& f01, Frag& f10, Frag& f11, Frag& fwb,
                   float4& fb0, float4& fb1) {
    const U16* p0 = w1p0 + (size_t)j * 2048;
    const U16* p1 = w1p1 + (size_t)j * 2048;
    f00.u4 = *(const uint4*)p0;
    f01.u4 = *(const uint4*)(p0 + 32);
    f10.u4 = *(const uint4*)p1;
    f11.u4 = *(const uint4*)(p1 + 32);
    fwb.u4 = *(const uint4*)(w2p + (size_t)j * 512);
    fb0 = *(const float4*)(b1p + j * 32);
    fb1 = *(const float4*)(b1p + j * 32 + 4);
  };
  auto comp = [&](Frag& f00, Frag& f01, Frag& f10, Frag& f11, Frag& fwb,
                  float4 fb0, float4 fb1) {
    f32x4_t cz0 = {fb0.x, fb0.y, fb0.z, fb0.w};
    f32x4_t cz1 = {fb1.x, fb1.y, fb1.z, fb1.w};
#pragma unroll
    for (int g = 0; g < 8; ++g) {
      f32x4_t z0 = cz0, z1 = cz1;
      z0 = __builtin_amdgcn_mfma_f32_16x16x32_bf16(f00.b8, bd[g][0].b8, z0, 0, 0, 0);
      z0 = __builtin_amdgcn_mfma_f32_16x16x32_bf16(f01.b8, bd[g][1].b8, z0, 0, 0, 0);
      z1 = __builtin_amdgcn_mfma_f32_16x16x32_bf16(f10.b8, bd[g][0].b8, z1, 0, 0, 0);
      z1 = __builtin_amdgcn_mfma_f32_16x16x32_bf16(f11.b8, bd[g][1].b8, z1, 0, 0, 0);
      float s0 = fast_silu(z0[0]), s1 = fast_silu(z0[1]);
      float s2 = fast_silu(z0[2]), s3 = fast_silu(z0[3]);
      float t0 = fast_silu(z1[0]), t1 = fast_silu(z1[1]);
      float t2 = fast_silu(z1[2]), t3 = fast_silu(z1[3]);
      Frag af2;
      af2.u[0] = cvt_pk_bf16(s0, s1); af2.u[1] = cvt_pk_bf16(s2, s3);
      af2.u[2] = cvt_pk_bf16(t0, t1); af2.u[3] = cvt_pk_bf16(t2, t3);
      bacc[g] = __builtin_amdgcn_mfma_f32_16x16x32_bf16(af2.b8, fwb.b8, bacc[g], 0, 0, 0);
    }
  };

  Frag e00, e01, e10, e11, ewb, o00, o01, o10, o11, owb;
  float4 eb0, eb1, ob0, ob1;
  loadw(0, e00, e01, e10, e11, ewb, eb0, eb1);
  for (int pp = 0; pp < 24; pp += 2) {
    loadw(pp + 1, o00, o01, o10, o11, owb, ob0, ob1);
    comp(e00, e01, e10, e11, ewb, eb0, eb1);
    if (pp + 2 < 24) loadw(pp + 2, e00, e01, e10, e11, ewb, eb0, eb1);
    comp(o00, o01, o10, o11, owb, ob0, ob1);
  }
  if (lm < 12) {
#pragma unroll
    for (int g = 0; g < 8; ++g) {
#pragma unroll
      for (int r = 0; r < 4; ++r) {
        int gr = r0 + (wave * 8 + g) * 16 + lq * 4 + r;
        int b = gr >> 16, rem = gr & 65535, i = rem >> 8, j = rem & 255;
        biasOut[(((size_t)b * 12 + lm) * 256 + i) * 256 + j] = bacc[g][r];
      }
    }
  }
}

// ---------------- merged launch: rb (0..511) + qkv/gate1 GEMM (512..1279) ----
__global__ __launch_bounds__(256) void qkvrb_kernel(
    const U16* __restrict__ xn, const U16* __restrict__ qg_wT,
    const float* __restrict__ qg_b, float* __restrict__ qkvb, U16* __restrict__ g1,
    const float* __restrict__ dist, const U16* __restrict__ rb1wT,
    const float* __restrict__ rb_b1, const U16* __restrict__ rb2wL,
    const float* __restrict__ rb_b2, float* __restrict__ biasB) {
  __shared__ __align__(16) U16 sA[2 * 2048];
  __shared__ __align__(16) U16 sB[2 * 2048];
  int bid = blockIdx.x;
  if (bid < 512) {
    rb_body(bid, dist, rb1wT, rb_b1, rb2wL, rb_b2, biasB);
  } else {
    int g = bid - 512;
    gemm_core<5, false>(sA, sB, xn, qg_wT, qg_b, nullptr, g1, qkvb, 3072, 768,
                        g % 48, g / 48);
  }
}

// ---------------- attention body (in-LDS K transpose; verified R8-R12) ----------------
__device__ void attn_body(unsigned char* smem, int bid, const float* qkv,
                          const float* biasB, const int* mask, float* ctx) {
  U16* sK = (U16*)smem;                          // 64*258*2 = 33024 B
  float(*sQ)[66] = (float(*)[66])(smem + 33024); // 16*66*4 = 4224 B
  float* sP = (float*)(smem + 33024 + 4224);     // 16*256*4 = 16384 B
  int tid = threadIdx.x, lane = tid & 63, w = tid >> 6;
  int bh = bid >> 4, b = bh / 12, h = bh % 12;
  int i0 = (bid & 15) * 16;
  {
    int r = tid >> 4, c = (tid & 15) * 4;
    *(float4*)&sQ[r][c] =
        *(const float4*)&qkv[((size_t)(b * 256 + i0 + r)) * 2304 + h * 64 + c];
  }
  {
    const float* kr = qkv + ((size_t)(b * 256 + w * 64)) * 2304 + 768 + h * 64 + lane;
#pragma unroll 8
    for (int rr = 0; rr < 64; ++rr) {
      float kv = kr[(size_t)rr * 2304];
      sK[lane * 258 + w * 64 + rr] = (U16)cvt_pk_bf16(kv, kv);
    }
  }
  __syncthreads();
  int iw = i0 + w * 4;
  float lacc[4][4] = {};
#pragma unroll 4
  for (int d = 0; d < 64; ++d) {
    float k0 = b2f(sK[d * 258 + lane]);
    float k1 = b2f(sK[d * 258 + 64 + lane]);
    float k2 = b2f(sK[d * 258 + 128 + lane]);
    float k3 = b2f(sK[d * 258 + 192 + lane]);
#pragma unroll
    for (int qi = 0; qi < 4; ++qi) {
      float qv = sQ[w * 4 + qi][d];
      lacc[qi][0] += qv * k0;
      lacc[qi][1] += qv * k1;
      lacc[qi][2] += qv * k2;
      lacc[qi][3] += qv * k3;
    }
  }
#pragma unroll
  for (int qi = 0; qi < 4; ++qi) {
    int gi = iw + qi;
    const float* brow = biasB + (((size_t)b * 12 + h) * 256 + gi) * 256;
    const int* mrow = mask + ((size_t)b * 256 + gi) * 256;
    float lg[4];
#pragma unroll
    for (int jc = 0; jc < 4; ++jc) {
      float lv = lacc[qi][jc] * 0.125f + brow[jc * 64 + lane];
      lg[jc] = mrow[jc * 64 + lane] ? lv : -1e30f;
    }
    float mx = fmaxf(fmaxf(lg[0], lg[1]), fmaxf(lg[2], lg[3]));
#pragma unroll
    for (int m = 32; m > 0; m >>= 1) mx = fmaxf(mx, __shfl_xor(mx, m));
    float e[4], sum = 0.f;
#pragma unroll
    for (int jc = 0; jc < 4; ++jc) { e[jc] = __expf(lg[jc] - mx); sum += e[jc]; }
#pragma unroll
    for (int m = 32; m > 0; m >>= 1) sum += __shfl_xor(sum, m);
    float inv = __builtin_amdgcn_rcpf(sum);
#pragma unroll
    for (int jc = 0; jc < 4; ++jc) sP[(w * 4 + qi) * 256 + jc * 64 + lane] = e[jc] * inv;
  }
  float ca[4] = {0.f, 0.f, 0.f, 0.f};
  const float* vcol = qkv + (size_t)b * 256 * 2304 + 1536 + h * 64 + lane;
#pragma unroll 2
  for (int j4 = 0; j4 < 256; j4 += 4) {
    float4 p0 = *(const float4*)&sP[(w * 4 + 0) * 256 + j4];
    float4 p1 = *(const float4*)&sP[(w * 4 + 1) * 256 + j4];
    float4 p2 = *(const float4*)&sP[(w * 4 + 2) * 256 + j4];
    float4 p3 = *(const float4*)&sP[(w * 4 + 3) * 256 + j4];
    const float* pp0 = (const float*)&p0;
    const float* pp1 = (const float*)&p1;
    const float* pp2 = (const float*)&p2;
    const float* pp3 = (const float*)&p3;
#pragma unroll
    for (int jj = 0; jj < 4; ++jj) {
      float v = vcol[(size_t)(j4 + jj) * 2304];
      ca[0] += pp0[jj] * v;
      ca[1] += pp1[jj] * v;
      ca[2] += pp2[jj] * v;
      ca[3] += pp3[jj] * v;
    }
  }
#pragma unroll
  for (int qi = 0; qi < 4; ++qi)
    ctx[((size_t)(b * 256 + iw + qi)) * 768 + h * 64 + lane] = ca[qi];
}

// ---------------- merged: attention (0..767) + gate2' sigmoid GEMM 32-tile (768..1151) ----
__global__ __launch_bounds__(256) void attn_gate_kernel(
    const float* __restrict__ qkv, const float* __restrict__ biasB,
    const int* __restrict__ mask, float* __restrict__ ctx,
    const U16* __restrict__ g1, const U16* __restrict__ g2wT,
    const float* __restrict__ gate_b2, U16* __restrict__ sg) {
  __shared__ __align__(16) unsigned char smem[53632];
  int bid = blockIdx.x;
  if (bid < 768) {
    attn_body(smem, bid, qkv, biasB, mask, ctx);
  } else {
    int g = bid - 768;  // 0..383: bx = g%12, by = g/12 (32-row tiles)
    gemm32_core<6, false>((U16*)smem, (U16*)(smem + 4096), g1, g2wT, gate_b2,
                          nullptr, sg, 768, 768, g % 12, g / 12);
  }
}

// ---------------- out-projection 32x64: x2 = (ctx .* sg) @ out_w + out_b + x ----------------
__global__ __launch_bounds__(256) void outp_kernel(const float* __restrict__ ctx,
                                                   const U16* __restrict__ sg,
                                                   const U16* __restrict__ out_wT,
                                                   const float* __restrict__ out_b,
                                                   const float* __restrict__ x,
                                                   float* __restrict__ x2) {
  __shared__ __align__(16) U16 sA[1024];      // 32x32 A tile (single buffer)
  __shared__ __align__(16) U16 sB[2 * 2048];  // 64x32 B dbuf
  int tid = threadIdx.x;
  int lane = tid & 63, wave = tid >> 6;
  int m0 = blockIdx.y * 32, n0 = blockIdx.x * 64;
  int wm = (wave >> 1) * 16, wn = (wave & 1) * 32;
  int lm = lane & 15, lq = lane >> 4;
  int srow = tid >> 2, scol = (tid & 3) * 8;
  const float* cg0 = ctx + (size_t)(m0 + srow) * 768 + scol;  // tid<128
  const U16* sg0 = sg + (size_t)(m0 + srow) * 768 + scol;
  const U16* bg = out_wT + (size_t)(n0 + srow) * 768 + scol;
  load_lds16(bg, sB + tid * 8);
  float4 ca0 = {}, ca1 = {};
  Frag sa; sa.u4 = make_uint4(0, 0, 0, 0);
  if (tid < 128) {
    ca0 = *(const float4*)cg0;
    ca1 = *(const float4*)(cg0 + 4);
    sa.u4 = *(const uint4*)sg0;
  }
  f32x4_t acc[2] = {};
  for (int i = 0; i < 24; ++i) {
    __syncthreads();  // prev frag reads done; current B (issued last iter) drained
    int cbB = (i & 1) * 2048, nbB = ((i + 1) & 1) * 2048;
    if (i + 1 < 24) load_lds16(bg + (i + 1) * 32, sB + nbB + tid * 8);
    if (tid < 128) {
      Frag av;
      av.u[0] = cvt_pk_bf16(ca0.x * b2f(sa.s[0]), ca0.y * b2f(sa.s[1]));
      av.u[1] = cvt_pk_bf16(ca0.z * b2f(sa.s[2]), ca0.w * b2f(sa.s[3]));
      av.u[2] = cvt_pk_bf16(ca1.x * b2f(sa.s[4]), ca1.y * b2f(sa.s[5]));
      av.u[3] = cvt_pk_bf16(ca1.z * b2f(sa.s[6]), ca1.w * b2f(sa.s[7]));
      *(uint4*)&sA[tid * 8] = av.u4;
      if (i + 1 < 24) {
        ca0 = *(const float4*)(cg0 + (i + 1) * 32);
        ca1 = *(const float4*)(cg0 + (i + 1) * 32 + 4);
        sa.u4 = *(const uint4*)(sg0 + (i + 1) * 32);
      }
    }
    __syncthreads();  // A writes visible (+ vmcnt drain)
    Frag af, bf[2];
    af.u4 = *(const uint4*)&sA[(wm + lm) * 32 + lq * 8];
#pragma unroll
    for (int nt = 0; nt < 2; ++nt)
      bf[nt].u4 = *(const uint4*)&sB[cbB + (wn + nt * 16 + lm) * 32 + lq * 8];
#pragma unroll
    for (int nt = 0; nt < 2; ++nt)
      acc[nt] = __builtin_amdgcn_mfma_f32_16x16x32_bf16(af.b8, bf[nt].b8,
                                                        acc[nt], 0, 0, 0);
  }
#pragma unroll
  for (int nt = 0; nt < 2; ++nt) {
    int gc = n0 + wn + nt * 16 + lm;
    float bz = out_b[gc];
#pragma unroll
    for (int r = 0; r < 4; ++r) {
      int gr = m0 + wm + lq * 4 + r;
      size_t idx = (size_t)gr * 768 + gc;
      x2[idx] = acc[nt][r] + bz + x[idx];
    }
  }
}

// ---------------- standalone LN (LN2) ----------------
__global__ __launch_bounds__(256) void ln_kernel(const float* __restrict__ X,
                                                 const float* __restrict__ gam,
                                                 const float* __restrict__ bet,
                                                 U16* __restrict__ Y) {
  ln_row(blockIdx.x, X, gam, bet, Y);
}

// ---------------- launcher ----------------
extern "C" void kernel_launch(void* const* d_in, const int* in_sizes, int n_in,
                              void* d_out, int out_size, void* d_ws, size_t ws_size,
                              hipStream_t stream) {
  const float* x       = (const float*)d_in[0];
  const float* dist    = (const float*)d_in[1];
  const int* mask      = (const int*)d_in[2];
  const float* qkv_w   = (const float*)d_in[3];
  const float* qkv_b   = (const float*)d_in[4];
  const float* out_w   = (const float*)d_in[5];
  const float* out_b   = (const float*)d_in[6];
  const float* rb_w1   = (const float*)d_in[7];
  const float* rb_b1   = (const float*)d_in[8];
  const float* rb_w2   = (const float*)d_in[9];
  const float* rb_b2   = (const float*)d_in[10];
  const float* gate_w1 = (const float*)d_in[11];
  const float* gate_b1 = (const float*)d_in[12];
  const float* gate_w2 = (const float*)d_in[13];
  const float* gate_b2 = (const float*)d_in[14];
  const float* ff_w1   = (const float*)d_in[15];
  const float* ff_b1   = (const float*)d_in[16];
  const float* ff_w2   = (const float*)d_in[17];
  const float* ff_b2   = (const float*)d_in[18];
  const float* ln1_g   = (const float*)d_in[19];
  const float* ln1_b   = (const float*)d_in[20];
  const float* ln2_g   = (const float*)d_in[21];
  const float* ln2_b   = (const float*)d_in[22];

  char* w = (char*)d_ws;
  auto alloc = [&](size_t bytes) {
    char* p = w;
    w += (bytes + 255) & ~(size_t)255;
    return p;
  };
  U16* xn      = (U16*)alloc(1024 * 768 * 2);
  float* qkvb  = (float*)alloc((size_t)1024 * 2304 * 4);
  U16* qg_wT   = (U16*)alloc((size_t)3072 * 768 * 2);
  U16* qkv_wT  = qg_wT;
  U16* g1wT    = qg_wT + (size_t)2304 * 768;
  float* qg_b  = (float*)alloc(3072 * 4);
  U16* out_wT  = (U16*)alloc(768 * 768 * 2);
  U16* g2wT    = (U16*)alloc(768 * 768 * 2);
  U16* ff1wT   = (U16*)alloc(1536 * 768 * 2);
  U16* ff2wT   = (U16*)alloc(768 * 1536 * 2);
  U16* rb1wT   = (U16*)alloc(768 * 64 * 2);
  U16* rb2wL   = (U16*)alloc(24 * 64 * 8 * 2);
  float* biasB = (float*)alloc((size_t)4 * 12 * 256 * 256 * 4);
  float* ctx   = (float*)alloc(1024 * 768 * 4);
  U16* g1      = (U16*)alloc(1024 * 768 * 2);
  U16* sg      = (U16*)alloc(1024 * 768 * 2);
  float* x2    = (float*)alloc(1024 * 768 * 4);
  U16* y       = (U16*)alloc(1024 * 768 * 2);
  U16* f1      = (U16*)alloc(1024 * 1536 * 2);
  (void)ws_size; (void)in_sizes; (void)n_in; (void)out_size;

  // 1: weight prep + LN1
  prep_kernel<<<6892, 256, 0, stream>>>(qkv_w, out_w, gate_w1, gate_w2, ff_w1, ff_w2,
                                        rb_w1, rb_w2, qkv_b, gate_b1,
                                        qkv_wT, out_wT, g1wT, g2wT, ff1wT, ff2wT,
                                        rb1wT, rb2wL, qg_b, x, ln1_g, ln1_b, xn);
  // 2: rb bias MLP (512, first) + fused qkv/gate1 GEMM (768)
  qkvrb_kernel<<<1280, 256, 0, stream>>>(xn, qg_wT, qg_b, qkvb, g1,
                                         dist, rb1wT, rb_b1, rb2wL, rb_b2, biasB);
  // 3: attention (768) + gate2' 32-tile (384)
  attn_gate_kernel<<<1152, 256, 0, stream>>>(qkvb, biasB, mask, ctx,
                                             g1, g2wT, gate_b2, sg);
  // 4: out projection, 32x64 tiles (384 blocks)
  outp_kernel<<<dim3(12, 32), 256, 0, stream>>>(ctx, sg, out_wT, out_b, x, x2);
  // 5: LN2
  ln_kernel<<<1024, 256, 0, stream>>>(x2, ln2_g, ln2_b, y);
  // 6: FF1 gelu, 32x64 tiles (768 blocks)
  gemm32_bt<2, false><<<dim3(24, 32), 256, 0, stream>>>(y, ff1wT, ff_b1, nullptr, f1,
                                                        1536, 768);
  // 7: FF2 + residual -> out, 32x64 tiles (384 blocks)
  gemm32_bt<4, true><<<dim3(12, 32), 256, 0, stream>>>(f1, ff2wT, ff_b2, x2,
                                                       (float*)d_out, 768, 1536);
}